// Round 1
// baseline (314.476 us; speedup 1.0000x reference)
//
#include <hip/hip_runtime.h>
#include <math.h>

#define L_SEQ 4096
#define D_HEAD 64
#define M_WIN 128
#define WIN 257              // 2*M+1
#define QB 8                 // query rows per block
#define W 264                // WIN + QB - 1 (window union width)
#define SCALE 0.125f         // 1/sqrt(64)

// Swizzled transposed-K LDS index for element (d, col):
// base d*W + (col XOR f(d)) with f(d) = (d>>2)&7.
// - Phase-B reads (lanes = consecutive cols, fixed d): XOR within aligned
//   8-blocks keeps 64 consecutive addresses -> conflict-free.
// - Staging writes (16 lanes share a row, d = 4*c4+j varies): banks become
//   (8j + row^f) with f varying over c4 -> 2-way (free) instead of 16-way.
__device__ __forceinline__ int kswz(int d, int col) {
    return d * W + (col ^ ((d >> 2) & 7));
}

__global__ __launch_bounds__(256, 2) void win_attn_kernel(
    const float* __restrict__ Q, const float* __restrict__ K,
    const float* __restrict__ V, float* __restrict__ OutO,
    float* __restrict__ OutA)
{
    extern __shared__ float smem[];
    float* k_t  = smem;                 // [64][W] swizzled, 16896 floats
    float* att  = smem + 64 * W;        // [QB][W], 2112 floats
    float* q_s  = att + QB * W;         // [QB][64], 512 floats
    float* part = smem;                 // alias over k_t after phase B: [4][QB][64]

    const int t   = threadIdx.x;
    const int bid = blockIdx.x;
    const int b   = bid >> 9;              // 512 q-blocks per batch
    const int q0  = (bid & 511) * QB;

    int s0 = q0 - M_WIN;
    if (s0 < 0) s0 = 0;
    if (s0 > L_SEQ - WIN) s0 = L_SEQ - WIN;
    const int wcount = (L_SEQ - s0 < W) ? (L_SEQ - s0) : W;   // valid union cols

    // ---------------- Phase A: stage Q and transposed K ----------------
    {
        const float4* Qg = (const float4*)(Q + ((size_t)(b * L_SEQ + q0)) * D_HEAD);
        if (t < QB * 16) ((float4*)q_s)[t] = Qg[t];

        const float4* Kg = (const float4*)(K + ((size_t)(b * L_SEQ + s0)) * D_HEAD);
        for (int idx = t; idx < wcount * 16; idx += 256) {
            int row = idx >> 4;          // 0..wcount-1
            int c4  = idx & 15;          // float4 chunk along d
            float4 kk = Kg[idx];         // coalesced
            int d0 = c4 * 4;
            k_t[kswz(d0 + 0, row)] = kk.x;
            k_t[kswz(d0 + 1, row)] = kk.y;
            k_t[kswz(d0 + 2, row)] = kk.z;
            k_t[kswz(d0 + 3, row)] = kk.w;
        }
    }
    __syncthreads();

    // ---------------- Phase B: raw scores for all union cols ----------------
    {
        const float4* q4 = (const float4*)q_s;      // [QB][16]
        for (int col = t; col < W; col += 256) {    // 256 cols + 8-col tail
            float acc[QB];
            #pragma unroll
            for (int q = 0; q < QB; ++q) acc[q] = 0.f;
            #pragma unroll
            for (int c = 0; c < 16; ++c) {
                float k0 = k_t[kswz(4 * c + 0, col)];
                float k1 = k_t[kswz(4 * c + 1, col)];
                float k2 = k_t[kswz(4 * c + 2, col)];
                float k3 = k_t[kswz(4 * c + 3, col)];
                #pragma unroll
                for (int q = 0; q < QB; ++q) {
                    float4 qv = q4[q * 16 + c];     // LDS broadcast
                    acc[q] += qv.x * k0 + qv.y * k1 + qv.z * k2 + qv.w * k3;
                }
            }
            #pragma unroll
            for (int q = 0; q < QB; ++q) att[q * W + col] = acc[q] * SCALE;
        }
    }
    __syncthreads();

    // ---------------- Phase C: masked softmax per q row (pre-normalized) ----
    {
        const int q  = t >> 5;            // 0..7
        const int i  = t & 31;
        const int qg = q0 + q;
        int st = qg - M_WIN;
        if (st < 0) st = 0;
        if (st > L_SEQ - WIN) st = L_SEQ - WIN;
        const int lo = st - s0;           // 0..QB-1

        float sv[9];
        float m = -1e30f;
        #pragma unroll
        for (int j = 0; j < 9; ++j) {
            int col = i + 32 * j;
            float s = -1e30f;
            if (col < W) {
                s = att[q * W + col];
                if (col < lo || col >= lo + WIN) s = -1e30f;   // window mask
            }
            sv[j] = s;
            m = fmaxf(m, s);
        }
        #pragma unroll
        for (int k = 16; k >= 1; k >>= 1) m = fmaxf(m, __shfl_xor(m, k));
        float sum = 0.f;
        #pragma unroll
        for (int j = 0; j < 9; ++j) {
            float e = (sv[j] <= -1e29f) ? 0.f : __expf(sv[j] - m);
            sv[j] = e;
            sum += e;
        }
        #pragma unroll
        for (int k = 16; k >= 1; k >>= 1) sum += __shfl_xor(sum, k);
        const float inv = 1.f / sum;
        #pragma unroll
        for (int j = 0; j < 9; ++j) {
            int col = i + 32 * j;
            if (col < W) att[q * W + col] = sv[j] * inv;   // exact 0 outside window
        }
    }
    __syncthreads();

    // ---------------- Phase D: stream full attention rows (the 537 MB) ------
    {
        #pragma unroll 1
        for (int ql = 0; ql < QB; ++ql) {
            float4* rowp = (float4*)(OutA + ((size_t)(b * L_SEQ + q0 + ql)) * L_SEQ);
            #pragma unroll
            for (int jj = 0; jj < 4; ++jj) {
                int f4i  = jj * 256 + t;
                int col0 = f4i * 4;
                int u    = col0 - s0;
                float4 w;
                w.x = (u     >= 0 && u     < W) ? att[ql * W + u]     : 0.f;
                w.y = (u + 1 >= 0 && u + 1 < W) ? att[ql * W + u + 1] : 0.f;
                w.z = (u + 2 >= 0 && u + 2 < W) ? att[ql * W + u + 2] : 0.f;
                w.w = (u + 3 >= 0 && u + 3 < W) ? att[ql * W + u + 3] : 0.f;
                rowp[f4i] = w;            // coalesced float4 stores
            }
        }
    }

    // ---------------- Phase E: PV (V straight from global, coalesced) -------
    {
        const int d  = t & 63;
        const int wq = t >> 6;            // each wave owns cols  wq + 4*j
        const float* Vg = V + ((size_t)(b * L_SEQ + s0)) * D_HEAD;
        float acc[QB];
        #pragma unroll
        for (int q = 0; q < QB; ++q) acc[q] = 0.f;
        #pragma unroll 2
        for (int j = 0; j < 66; ++j) {
            int col = wq + 4 * j;
            float vv = (col < wcount) ? Vg[(size_t)col * D_HEAD + d] : 0.f;
            #pragma unroll
            for (int q = 0; q < QB; ++q)
                acc[q] += att[q * W + col] * vv;   // att broadcast * v
        }
        #pragma unroll
        for (int q = 0; q < QB; ++q)
            part[(wq * QB + q) * 64 + d] = acc[q];   // k_t is dead; reuse as scratch
    }
    __syncthreads();

    // ---------------- Reduce cross-wave partials, write out ------------------
    {
        for (int idx = t; idx < QB * 64; idx += 256) {
            int q = idx >> 6, d = idx & 63;
            float o = part[(0 * QB + q) * 64 + d] + part[(1 * QB + q) * 64 + d]
                    + part[(2 * QB + q) * 64 + d] + part[(3 * QB + q) * 64 + d];
            OutO[((size_t)(b * L_SEQ + q0 + q)) * D_HEAD + d] = o;
        }
    }
}

extern "C" void kernel_launch(void* const* d_in, const int* in_sizes, int n_in,
                              void* d_out, int out_size, void* d_ws, size_t ws_size,
                              hipStream_t stream) {
    const float* Q = (const float*)d_in[0];
    const float* K = (const float*)d_in[1];
    const float* V = (const float*)d_in[2];
    float* OutO = (float*)d_out;
    float* OutA = OutO + (size_t)8 * L_SEQ * D_HEAD;   // attention follows out

    const int smem_bytes = (64 * W + QB * W + QB * 64) * 4;   // 78080 B
    hipFuncSetAttribute((const void*)win_attn_kernel,
                        hipFuncAttributeMaxDynamicSharedMemorySize, smem_bytes);

    dim3 grid(8 * (L_SEQ / QB));   // 4096 blocks: (batch, 8-row q-tile)
    dim3 block(256);
    win_attn_kernel<<<grid, block, smem_bytes, stream>>>(Q, K, V, OutO, OutA);
}